// Round 8
// baseline (106.626 us; speedup 1.0000x reference)
//
#include <hip/hip_runtime.h>
#include <math.h>

#define LL 768
#define CT 64
#define KD 192
#define OC 1024
#define NJS 48    // j-strips of 16 (rp strips)
#define NISW 192  // i-strips of 4 (cp strips, one per wave)

// ---------------- K1 k_mega: ONE pass over feat, no barriers ----------------
// block = 16x16 pair tile; wave w owns rows i0+4w..i0+4w+3 EXCLUSIVELY.
// Phase A: lane = (r2 = ln>>4, c = ln&15) -> pair (i0+4w+r2, j0+c).
//   16 contiguous-in-lane float4 loads (pair's 64 ch = 256B), dot in regs
//   (Wq uniform -> scalar loads), ONE exp per pair. No cross-lane reduce.
//   e -> er[w][*] (per-wave LDS) + e_buf (for z in k_combine).
// Phase B: lane = (u = ln>>4, q = ln&15); re-read the wave's 16KB coalesced
//   (L1/L2/L3-hot -> no extra HBM). Col partials in regs (cols m*4+u),
//   row partials folded over u via 2 shfl per row, written by u==0 lanes.
__global__ __launch_bounds__(256) void k_mega(const float* __restrict__ feat,
                                              const float* __restrict__ Wq,
                                              const float* __restrict__ bq,
                                              float* __restrict__ e_buf,
                                              float* __restrict__ rp,
                                              float* __restrict__ cp) {
    __shared__ float er[4][64];
    int t = threadIdx.x;
    int w = t >> 6, ln = t & 63;
    int bi = blockIdx.x / NJS, bj = blockIdx.x % NJS;
    int i0 = bi * 16 + w * 4;    // wave's 4 rows
    int j0 = bj * 16;

    // ---------------- phase A ----------------
    {
        int r2 = ln >> 4, c = ln & 15;
        const float4* pa = reinterpret_cast<const float4*>(
            feat + ((size_t)(i0 + r2) * LL + (j0 + c)) * CT);
        const float4* wq4 = reinterpret_cast<const float4*>(Wq);
        float4 da = make_float4(0.f, 0.f, 0.f, 0.f);
        #pragma unroll
        for (int k = 0; k < 16; ++k) {
            const float4 f = pa[k];
            const float4 wk = wq4[k];     // uniform across block -> SGPRs
            da.x = fmaf(f.x, wk.x, da.x);
            da.y = fmaf(f.y, wk.y, da.y);
            da.z = fmaf(f.z, wk.z, da.z);
            da.w = fmaf(f.w, wk.w, da.w);
        }
        float e = __expf((da.x + da.y) + (da.z + da.w) + bq[0]);
        er[w][ln] = e;
        e_buf[(size_t)(i0 + r2) * LL + j0 + c] = e;
    }
    // no __syncthreads: er[w] is produced and consumed by wave w only;
    // compiler inserts the lgkmcnt wait before the dependent ds_read.

    // ---------------- phase B ----------------
    int u = ln >> 4, q = ln & 15;
    float4 cr0 = make_float4(0,0,0,0), cr1 = make_float4(0,0,0,0);
    float4 cr2 = make_float4(0,0,0,0), cr3 = make_float4(0,0,0,0);

    #pragma unroll
    for (int r = 0; r < 4; ++r) {
        const float* fb = feat + ((size_t)(i0 + r) * LL + j0) * CT + q * 4;
        float4 rt = make_float4(0,0,0,0);

        #define BSTEP(M, CR)                                                  \
            {                                                                 \
                const float4 f = *reinterpret_cast<const float4*>(fb + (M * 4 + u) * CT); \
                float ee = er[w][r * 16 + M * 4 + u];                         \
                rt.x = fmaf(ee, f.x, rt.x);                                   \
                rt.y = fmaf(ee, f.y, rt.y);                                   \
                rt.z = fmaf(ee, f.z, rt.z);                                   \
                rt.w = fmaf(ee, f.w, rt.w);                                   \
                CR.x = fmaf(ee, f.x, CR.x);                                   \
                CR.y = fmaf(ee, f.y, CR.y);                                   \
                CR.z = fmaf(ee, f.z, CR.z);                                   \
                CR.w = fmaf(ee, f.w, CR.w);                                   \
            }
        BSTEP(0, cr0)
        BSTEP(1, cr1)
        BSTEP(2, cr2)
        BSTEP(3, cr3)
        #undef BSTEP

        // fold row partial over the 4 u-lanes
        rt.x += __shfl_xor(rt.x, 16); rt.x += __shfl_xor(rt.x, 32);
        rt.y += __shfl_xor(rt.y, 16); rt.y += __shfl_xor(rt.y, 32);
        rt.z += __shfl_xor(rt.z, 16); rt.z += __shfl_xor(rt.z, 32);
        rt.w += __shfl_xor(rt.w, 16); rt.w += __shfl_xor(rt.w, 32);
        if (u == 0)
            *reinterpret_cast<float4*>(rp + ((size_t)bj * LL + i0 + r) * CT + q * 4) = rt;
    }

    // col partials: strip = bi*4 + w (the wave's exclusive 4-row band)
    {
        int s = bi * 4 + w;
        size_t cb = ((size_t)s * LL + j0 + u) * CT + q * 4;
        *reinterpret_cast<float4*>(cp + cb + (size_t)(0 * 4) * CT) = cr0;
        *reinterpret_cast<float4*>(cp + cb + (size_t)(1 * 4) * CT) = cr1;
        *reinterpret_cast<float4*>(cp + cb + (size_t)(2 * 4) * CT) = cr2;
        *reinterpret_cast<float4*>(cp + cb + (size_t)(3 * 4) * CT) = cr3;
    }
}

// ---------------- K2 k_combine: fold partials + z from e_buf -> rcfeat -------
// grid (48, 2): 16 lines per block. side 0 = rows (rp, 48 strips),
// side 1 = cols (cp, 192 strips). z computed from e_buf.
__global__ __launch_bounds__(256) void k_combine(const float* __restrict__ rp,
                                                 const float* __restrict__ cp,
                                                 const float* __restrict__ e_buf,
                                                 float* __restrict__ rcfeat) {
    int t = threadIdx.x;
    int r = t >> 4, q = t & 15;
    int L0 = blockIdx.x * 16;
    int side = blockIdx.y;

    float4 acc = make_float4(0.f, 0.f, 0.f, 0.f);
    float z = 0.f;
    if (side == 0) {
        #pragma unroll 4
        for (int s = 0; s < NJS; ++s) {
            const float4 v = *reinterpret_cast<const float4*>(
                rp + ((size_t)s * LL + L0 + r) * CT + q * 4);
            acc.x += v.x; acc.y += v.y; acc.z += v.z; acc.w += v.w;
        }
        const float* erow = e_buf + (size_t)(L0 + r) * LL + q;
        #pragma unroll 4
        for (int kk = 0; kk < 48; ++kk) z += erow[kk * 16];
    } else {
        #pragma unroll 4
        for (int s = 0; s < NISW; ++s) {
            const float4 v = *reinterpret_cast<const float4*>(
                cp + ((size_t)s * LL + L0 + r) * CT + q * 4);
            acc.x += v.x; acc.y += v.y; acc.z += v.z; acc.w += v.w;
        }
        const float* ecol = e_buf + (size_t)q * LL + L0 + r;
        #pragma unroll 4
        for (int kk = 0; kk < 48; ++kk) z += ecol[(size_t)kk * 16 * LL];
    }
    // fold z over the 16 q-lanes (row/col of this line)
    z += __shfl_xor(z, 1);
    z += __shfl_xor(z, 2);
    z += __shfl_xor(z, 4);
    z += __shfl_xor(z, 8);
    float inv = 1.0f / z;
    acc.x *= inv; acc.y *= inv; acc.z *= inv; acc.w *= inv;
    *reinterpret_cast<float4*>(rcfeat + (size_t)side * LL * CT
                               + (L0 + r) * CT + q * 4) = acc;
}

// ---------------- K3: diag gather + LN + (x @ W + b) [*sigma] ----------------
__global__ __launch_bounds__(256) void k_final(const float* __restrict__ feat,
                                               const float* __restrict__ rcfeat,
                                               const float* __restrict__ ln_g,
                                               const float* __restrict__ ln_b,
                                               const float* __restrict__ WU,
                                               const float* __restrict__ bU,
                                               const float* __restrict__ WV,
                                               const float* __restrict__ bV,
                                               const float* __restrict__ sigma,
                                               float* __restrict__ out) {
    __shared__ float xbuf[8][KD];
    int t = threadIdx.x;
    int wid = t >> 6, l = t & 63;
    int r0 = blockIdx.x * 8;
    int right = blockIdx.y;
    const float* rfeat = rcfeat;
    const float* cfeat = rcfeat + LL * CT;

    for (int r = wid; r < 8; r += 4) {
        int i = r0 + r;
        float d  = feat[((size_t)i * LL + i) * CT + l];
        float rv = rfeat[(size_t)i * CT + l];
        float cv = cfeat[(size_t)i * CT + l];
        float sum = d + rv + cv;
        #pragma unroll
        for (int o = 32; o; o >>= 1) sum += __shfl_xor(sum, o);
        float mu = sum * (1.0f / 192.0f);
        float d0 = d - mu, d1 = rv - mu, d2 = cv - mu;
        float sq = d0 * d0 + d1 * d1 + d2 * d2;
        #pragma unroll
        for (int o = 32; o; o >>= 1) sq += __shfl_xor(sq, o);
        float rstd = rsqrtf(sq * (1.0f / 192.0f) + 1e-5f);
        float h0 = d0 * rstd, h1 = d1 * rstd, h2 = d2 * rstd;
        float a1 = right ? h2 : h1;
        float a2 = right ? h1 : h2;
        xbuf[r][l]       = h0 * ln_g[l]       + ln_b[l];
        xbuf[r][64 + l]  = a1 * ln_g[64 + l]  + ln_b[64 + l];
        xbuf[r][128 + l] = a2 * ln_g[128 + l] + ln_b[128 + l];
    }
    __syncthreads();

    const float* W    = right ? WV : WU;
    const float* bias = right ? bV : bU;
    int o = t * 4;
    float4 acc[8];
    #pragma unroll
    for (int r = 0; r < 8; ++r) acc[r] = make_float4(0.f, 0.f, 0.f, 0.f);

    for (int k = 0; k < KD; k += 4) {
        float4 xr[8];
        #pragma unroll
        for (int r = 0; r < 8; ++r)
            xr[r] = *reinterpret_cast<const float4*>(&xbuf[r][k]);
        #pragma unroll
        for (int kk = 0; kk < 4; ++kk) {
            float4 wv = *reinterpret_cast<const float4*>(W + (size_t)(k + kk) * OC + o);
            #pragma unroll
            for (int r = 0; r < 8; ++r) {
                float xv = (&xr[r].x)[kk];
                acc[r].x = fmaf(xv, wv.x, acc[r].x);
                acc[r].y = fmaf(xv, wv.y, acc[r].y);
                acc[r].z = fmaf(xv, wv.z, acc[r].z);
                acc[r].w = fmaf(xv, wv.w, acc[r].w);
            }
        }
    }

    float4 bb = *reinterpret_cast<const float4*>(bias + o);
    float sg = right ? 1.0f : sigma[o >> 7];
    float* obase = out + (right ? (size_t)LL * OC : 0);
    #pragma unroll
    for (int r = 0; r < 8; ++r) {
        float4 v;
        v.x = (acc[r].x + bb.x) * sg;
        v.y = (acc[r].y + bb.y) * sg;
        v.z = (acc[r].z + bb.z) * sg;
        v.w = (acc[r].w + bb.w) * sg;
        *reinterpret_cast<float4*>(obase + (size_t)(r0 + r) * OC + o) = v;
    }
}

extern "C" void kernel_launch(void* const* d_in, const int* in_sizes, int n_in,
                              void* d_out, int out_size, void* d_ws, size_t ws_size,
                              hipStream_t stream) {
    const float* feat  = (const float*)d_in[0];
    const float* Wq    = (const float*)d_in[1];
    const float* bq    = (const float*)d_in[2];
    const float* ln_g  = (const float*)d_in[3];
    const float* ln_b  = (const float*)d_in[4];
    const float* WU    = (const float*)d_in[5];
    const float* bU    = (const float*)d_in[6];
    const float* WV    = (const float*)d_in[7];
    const float* bV    = (const float*)d_in[8];
    const float* sigma = (const float*)d_in[9];
    float* out = (float*)d_out;

    float* ws     = (float*)d_ws;
    float* e_buf  = ws;                                   // LL*LL
    float* rp     = e_buf + (size_t)LL * LL;              // NJS*LL*CT
    float* cp     = rp + (size_t)NJS * LL * CT;           // NISW*LL*CT
    float* rcfeat = cp + (size_t)NISW * LL * CT;          // 2*LL*CT

    hipLaunchKernelGGL(k_mega, dim3((LL / 16) * (LL / 16)), dim3(256), 0, stream,
                       feat, Wq, bq, e_buf, rp, cp);
    hipLaunchKernelGGL(k_combine, dim3(LL / 16, 2), dim3(256), 0, stream,
                       rp, cp, e_buf, rcfeat);
    hipLaunchKernelGGL(k_final, dim3(LL / 8, 2), dim3(256), 0, stream,
                       feat, rcfeat, ln_g, ln_b, WU, bU, WV, bV, sigma, out);
}

// Round 9
// 75.586 us; speedup vs baseline: 1.4107x; 1.4107x over previous
//
#include <hip/hip_runtime.h>
#include <math.h>

#define LL 768
#define CT 64
#define KD 192
#define OC 1024
#define TS 16
#define NST 48           // 768/16 tiles per dim
#define PCH 68           // partial line: 64 ch + z at [64], padded to 68

// 16-lane-group sum via DPP: quad_perm(xor1), quad_perm(xor2), row_ror:4,
// row_ror:8 — pure VALU, no DS ops, no lgkm waits. Verified on-device (R6).
__device__ __forceinline__ float sum16(float x) {
    x += __int_as_float(__builtin_amdgcn_update_dpp(0, __float_as_int(x), 0xB1, 0xF, 0xF, true));
    x += __int_as_float(__builtin_amdgcn_update_dpp(0, __float_as_int(x), 0x4E, 0xF, 0xF, true));
    x += __int_as_float(__builtin_amdgcn_update_dpp(0, __float_as_int(x), 0x124, 0xF, 0xF, true));
    x += __int_as_float(__builtin_amdgcn_update_dpp(0, __float_as_int(x), 0x128, 0xF, 0xF, true));
    return x;
}

// ---------------- K1: fused logits+exp+row/col sums, 1 feat pass ----------------
// R4 structure (measured best, 82.6): 16x16 pair tile, thread (u=t>>4 col,
// q=t&15 channel quad), per i-iter 1KB/wave contiguous load. Deltas vs R4:
//   - dot-reduce via DPP (VALU) instead of 4x ds_swizzle (~480cyc DS chain)
//   - explicit 2-deep load prefetch (>=2 loads in flight per wave)
//   - __launch_bounds__(256,6) to hold >=6 blocks/CU occupancy
__global__ __launch_bounds__(256, 6) void k_fused(const float* __restrict__ feat,
                                                  const float* __restrict__ Wq,
                                                  const float* __restrict__ bq,
                                                  float* __restrict__ rp,
                                                  float* __restrict__ cp) {
    __shared__ float4 lbuf[16][8][17];   // [u][ii][c4 pad 17]
    __shared__ float  zb[16][9];         // per-(u, ii) row-z contribution

    int t = threadIdx.x;
    int u = t >> 4, q = t & 15;
    int bi = blockIdx.x, bj = blockIdx.y;
    int i0 = bi * TS, j0 = bj * TS;

    const float4 wq = *reinterpret_cast<const float4*>(Wq + q * 4);
    const float bqv = bq[0];

    const float* fb = feat + ((size_t)i0 * LL + j0 + u) * CT + q * 4;
    const size_t istr = (size_t)LL * CT;
    float4 creg = make_float4(0.f, 0.f, 0.f, 0.f);
    float zc = 0.f;

    float4 fnext = *reinterpret_cast<const float4*>(fb);

    #pragma unroll 2
    for (int half = 0; half < 2; ++half) {
        #pragma unroll
        for (int ii = 0; ii < 8; ++ii) {
            const int idx = half * 8 + ii;
            const float4 f = fnext;
            if (idx < 15)
                fnext = *reinterpret_cast<const float4*>(fb + (size_t)(idx + 1) * istr);

            float s = f.x * wq.x + f.y * wq.y + f.z * wq.z + f.w * wq.w;
            s = sum16(s);                    // DPP, pure VALU
            float e = __expf(s + bqv);

            float4 p;
            p.x = e * f.x; p.y = e * f.y; p.z = e * f.z; p.w = e * f.w;

            // col accumulation (register)
            creg.x += p.x; creg.y += p.y; creg.z += p.z; creg.w += p.w;
            zc += e;

            // row contribution: one LDS write (assignment, no RMW, no shuffles)
            lbuf[u][ii][q] = p;
            if (q == 0) zb[u][ii] = e;
        }
        __syncthreads();

        // fold row partials over the 16 u-columns
        if (t < 128) {
            int ii = t >> 4, c4 = t & 15;
            float4 a = make_float4(0.f, 0.f, 0.f, 0.f);
            #pragma unroll
            for (int uu = 0; uu < 16; ++uu) {
                const float4 v = lbuf[uu][ii][c4];
                a.x += v.x; a.y += v.y; a.z += v.z; a.w += v.w;
            }
            *reinterpret_cast<float4*>(rp + ((size_t)bj * LL + i0 + half * 8 + ii) * PCH
                                       + c4 * 4) = a;
        }
        if (t < 8) {
            float zz = 0.f;
            #pragma unroll
            for (int uu = 0; uu < 16; ++uu) zz += zb[uu][t];
            rp[((size_t)bj * LL + i0 + half * 8 + t) * PCH + 64] = zz;
        }
        __syncthreads();
    }

    // col partials out (registers -> global, once)
    size_t cpo = ((size_t)bi * LL + (j0 + u)) * PCH;
    *reinterpret_cast<float4*>(cp + cpo + q * 4) = creg;
    if (q == 0) cp[cpo + 64] = zc;
}

// ---------------- K2: fold 48 strip-partials, divide by z -> rcfeat ----------
__global__ __launch_bounds__(256) void k_combine(const float* __restrict__ rp,
                                                 const float* __restrict__ cp,
                                                 float* __restrict__ rcfeat) {
    int t = threadIdx.x;
    int r = t >> 4, q = t & 15;
    int L0 = blockIdx.x * 16;
    int side = blockIdx.y;
    const float* base = side ? cp : rp;

    float4 acc = make_float4(0.f, 0.f, 0.f, 0.f);
    float z = 0.f;
    #pragma unroll 4
    for (int s = 0; s < NST; ++s) {
        const float* p = base + ((size_t)s * LL + L0 + r) * PCH;
        const float4 v = *reinterpret_cast<const float4*>(p + q * 4);
        acc.x += v.x; acc.y += v.y; acc.z += v.z; acc.w += v.w;
        z += p[64];
    }
    float inv = 1.0f / z;
    acc.x *= inv; acc.y *= inv; acc.z *= inv; acc.w *= inv;
    *reinterpret_cast<float4*>(rcfeat + (size_t)side * LL * CT
                               + (L0 + r) * CT + q * 4) = acc;
}

// ---------------- K3: diag gather + LN + (x @ W + b) [*sigma] ----------------
__global__ __launch_bounds__(256) void k_final(const float* __restrict__ feat,
                                               const float* __restrict__ rcfeat,
                                               const float* __restrict__ ln_g,
                                               const float* __restrict__ ln_b,
                                               const float* __restrict__ WU,
                                               const float* __restrict__ bU,
                                               const float* __restrict__ WV,
                                               const float* __restrict__ bV,
                                               const float* __restrict__ sigma,
                                               float* __restrict__ out) {
    __shared__ float xbuf[8][KD];
    int t = threadIdx.x;
    int wid = t >> 6, l = t & 63;
    int r0 = blockIdx.x * 8;
    int right = blockIdx.y;
    const float* rfeat = rcfeat;
    const float* cfeat = rcfeat + LL * CT;

    for (int r = wid; r < 8; r += 4) {
        int i = r0 + r;
        float d  = feat[((size_t)i * LL + i) * CT + l];
        float rv = rfeat[(size_t)i * CT + l];
        float cv = cfeat[(size_t)i * CT + l];
        float sum = d + rv + cv;
        #pragma unroll
        for (int o = 32; o; o >>= 1) sum += __shfl_xor(sum, o);
        float mu = sum * (1.0f / 192.0f);
        float d0 = d - mu, d1 = rv - mu, d2 = cv - mu;
        float sq = d0 * d0 + d1 * d1 + d2 * d2;
        #pragma unroll
        for (int o = 32; o; o >>= 1) sq += __shfl_xor(sq, o);
        float rstd = rsqrtf(sq * (1.0f / 192.0f) + 1e-5f);
        float h0 = d0 * rstd, h1 = d1 * rstd, h2 = d2 * rstd;
        float a1 = right ? h2 : h1;
        float a2 = right ? h1 : h2;
        xbuf[r][l]       = h0 * ln_g[l]       + ln_b[l];
        xbuf[r][64 + l]  = a1 * ln_g[64 + l]  + ln_b[64 + l];
        xbuf[r][128 + l] = a2 * ln_g[128 + l] + ln_b[128 + l];
    }
    __syncthreads();

    const float* W    = right ? WV : WU;
    const float* bias = right ? bV : bU;
    int o = t * 4;
    float4 acc[8];
    #pragma unroll
    for (int r = 0; r < 8; ++r) acc[r] = make_float4(0.f, 0.f, 0.f, 0.f);

    for (int k = 0; k < KD; k += 4) {
        float4 xr[8];
        #pragma unroll
        for (int r = 0; r < 8; ++r)
            xr[r] = *reinterpret_cast<const float4*>(&xbuf[r][k]);
        #pragma unroll
        for (int kk = 0; kk < 4; ++kk) {
            float4 wv = *reinterpret_cast<const float4*>(W + (size_t)(k + kk) * OC + o);
            #pragma unroll
            for (int r = 0; r < 8; ++r) {
                float xv = (&xr[r].x)[kk];
                acc[r].x = fmaf(xv, wv.x, acc[r].x);
                acc[r].y = fmaf(xv, wv.y, acc[r].y);
                acc[r].z = fmaf(xv, wv.z, acc[r].z);
                acc[r].w = fmaf(xv, wv.w, acc[r].w);
            }
        }
    }

    float4 bb = *reinterpret_cast<const float4*>(bias + o);
    float sg = right ? 1.0f : sigma[o >> 7];
    float* obase = out + (right ? (size_t)LL * OC : 0);
    #pragma unroll
    for (int r = 0; r < 8; ++r) {
        float4 v;
        v.x = (acc[r].x + bb.x) * sg;
        v.y = (acc[r].y + bb.y) * sg;
        v.z = (acc[r].z + bb.z) * sg;
        v.w = (acc[r].w + bb.w) * sg;
        *reinterpret_cast<float4*>(obase + (size_t)(r0 + r) * OC + o) = v;
    }
}

extern "C" void kernel_launch(void* const* d_in, const int* in_sizes, int n_in,
                              void* d_out, int out_size, void* d_ws, size_t ws_size,
                              hipStream_t stream) {
    const float* feat  = (const float*)d_in[0];
    const float* Wq    = (const float*)d_in[1];
    const float* bq    = (const float*)d_in[2];
    const float* ln_g  = (const float*)d_in[3];
    const float* ln_b  = (const float*)d_in[4];
    const float* WU    = (const float*)d_in[5];
    const float* bU    = (const float*)d_in[6];
    const float* WV    = (const float*)d_in[7];
    const float* bV    = (const float*)d_in[8];
    const float* sigma = (const float*)d_in[9];
    float* out = (float*)d_out;

    float* ws     = (float*)d_ws;
    float* rp     = ws;                                  // NST*LL*PCH
    float* cp     = rp + (size_t)NST * LL * PCH;         // NST*LL*PCH
    float* rcfeat = cp + (size_t)NST * LL * PCH;         // 2*LL*CT

    hipLaunchKernelGGL(k_fused, dim3(NST, NST), dim3(256), 0, stream,
                       feat, Wq, bq, rp, cp);
    hipLaunchKernelGGL(k_combine, dim3(NST, 2), dim3(256), 0, stream,
                       rp, cp, rcfeat);
    hipLaunchKernelGGL(k_final, dim3(LL / 8, 2), dim3(256), 0, stream,
                       feat, rcfeat, ln_g, ln_b, WU, bU, WV, bV, sigma, out);
}